// Round 1
// baseline (1952.628 us; speedup 1.0000x reference)
//
#include <hip/hip_runtime.h>

#define N_SAMP 8192
#define NDIM   3072
#define NK     64
#define NS     48
#define MK     200   // knots per transform

__device__ __forceinline__ float rcp_fast(float x) { return __builtin_amdgcn_rcpf(x); }

// ---------------------------------------------------------------------------
// Kernel 1: 64 independent 48x48 QR factorizations (modified Gram-Schmidt).
// Register-column layout: lane j owns column j. MGS produces the unique Q with
// positive-diagonal R, which equals the reference's sign-fixed QR exactly.
// ---------------------------------------------------------------------------
__global__ __launch_bounds__(64) void qr_kernel(const float* __restrict__ Araw,
                                                float* __restrict__ Qws) {
  const int k = blockIdx.x;
  const int lane = threadIdx.x;
  const float* Ak = Araw + k * NS * NS;
  float col[NS];
#pragma unroll
  for (int r = 0; r < NS; ++r)
    col[r] = (lane < NS) ? Ak[r * NS + lane] : 0.f;   // coalesced: lanes = j

  for (int j = 0; j < NS; ++j) {
    float q[NS];
#pragma unroll
    for (int r = 0; r < NS; ++r)
      q[r] = __int_as_float(__builtin_amdgcn_readlane(__float_as_int(col[r]), j));
    float n0 = 0.f, n1 = 0.f, n2 = 0.f, n3 = 0.f;
#pragma unroll
    for (int r = 0; r < NS; r += 4) {
      n0 = fmaf(q[r+0], q[r+0], n0); n1 = fmaf(q[r+1], q[r+1], n1);
      n2 = fmaf(q[r+2], q[r+2], n2); n3 = fmaf(q[r+3], q[r+3], n3);
    }
    float rinv = 1.0f / sqrtf((n0 + n1) + (n2 + n3));
#pragma unroll
    for (int r = 0; r < NS; ++r) q[r] *= rinv;
    if (lane == j) {
#pragma unroll
      for (int r = 0; r < NS; ++r) col[r] = q[r];
    } else if (lane > j && lane < NS) {
      float d0 = 0.f, d1 = 0.f, d2 = 0.f, d3 = 0.f;
#pragma unroll
      for (int r = 0; r < NS; r += 4) {
        d0 = fmaf(q[r+0], col[r+0], d0); d1 = fmaf(q[r+1], col[r+1], d1);
        d2 = fmaf(q[r+2], col[r+2], d2); d3 = fmaf(q[r+3], col[r+3], d3);
      }
      float dt = (d0 + d1) + (d2 + d3);
#pragma unroll
      for (int r = 0; r < NS; ++r) col[r] = fmaf(-dt, q[r], col[r]);
    }
  }
  if (lane < NS) {
    float* Qk = Qws + k * NS * NS;           // row-major Q[d][j]
#pragma unroll
    for (int r = 0; r < NS; ++r) Qk[r * NS + lane] = col[r];
  }
}

// ---------------------------------------------------------------------------
// Kernel 2: build knot tables. One wave per transform row t.
//  xxws[t][0..199]   raw knot x positions (cumsum of exp(logdx))
//  yp[t][m] = (yy[m], yy[m+1])   float2 pairs
//  dp[t][m] = (delta[m], delta[m+1])
// ---------------------------------------------------------------------------
__global__ __launch_bounds__(256) void knots_kernel(
    const float* __restrict__ x0, const float* __restrict__ logdx,
    const float* __restrict__ y0, const float* __restrict__ logdy,
    const float* __restrict__ logderiv,
    float* __restrict__ xxws, float2* __restrict__ yp, float2* __restrict__ dp) {
  const int wid = threadIdx.x >> 6, lane = threadIdx.x & 63;
  const int t = blockIdx.x * 4 + wid;
  __shared__ float syy[4][MK];

  // ---- xx scan ----
  {
    const float* row = logdx + t * (MK - 1);
    int i0 = lane * 4;
    float e0 = (i0 + 0 < MK - 1) ? __expf(row[i0 + 0]) : 0.f;
    float e1 = (i0 + 1 < MK - 1) ? __expf(row[i0 + 1]) : 0.f;
    float e2 = (i0 + 2 < MK - 1) ? __expf(row[i0 + 2]) : 0.f;
    float e3 = (i0 + 3 < MK - 1) ? __expf(row[i0 + 3]) : 0.f;
    float p0 = e0, p1 = p0 + e1, p2 = p1 + e2, p3 = p2 + e3;
    float incl = p3;
#pragma unroll
    for (int off = 1; off < 64; off <<= 1) {
      float u = __shfl_up(incl, off, 64);
      if (lane >= off) incl += u;
    }
    float xv = x0[t];
    float base = xv + (incl - p3);           // exclusive prefix + x0
    float* xrow = xxws + t * MK;
    if (lane == 0) xrow[0] = xv;
    if (i0 + 0 < MK - 1) xrow[1 + i0 + 0] = base + p0;
    if (i0 + 1 < MK - 1) xrow[1 + i0 + 1] = base + p1;
    if (i0 + 2 < MK - 1) xrow[1 + i0 + 2] = base + p2;
    if (i0 + 3 < MK - 1) xrow[1 + i0 + 3] = base + p3;
  }
  // ---- yy scan (into LDS) ----
  {
    const float* row = logdy + t * (MK - 1);
    int i0 = lane * 4;
    float e0 = (i0 + 0 < MK - 1) ? __expf(row[i0 + 0]) : 0.f;
    float e1 = (i0 + 1 < MK - 1) ? __expf(row[i0 + 1]) : 0.f;
    float e2 = (i0 + 2 < MK - 1) ? __expf(row[i0 + 2]) : 0.f;
    float e3 = (i0 + 3 < MK - 1) ? __expf(row[i0 + 3]) : 0.f;
    float p0 = e0, p1 = p0 + e1, p2 = p1 + e2, p3 = p2 + e3;
    float incl = p3;
#pragma unroll
    for (int off = 1; off < 64; off <<= 1) {
      float u = __shfl_up(incl, off, 64);
      if (lane >= off) incl += u;
    }
    float yv = y0[t];
    float base = yv + (incl - p3);
    if (lane == 0) syy[wid][0] = yv;
    if (i0 + 0 < MK - 1) syy[wid][1 + i0 + 0] = base + p0;
    if (i0 + 1 < MK - 1) syy[wid][1 + i0 + 1] = base + p1;
    if (i0 + 2 < MK - 1) syy[wid][1 + i0 + 2] = base + p2;
    if (i0 + 3 < MK - 1) syy[wid][1 + i0 + 3] = base + p3;
  }
  __syncthreads();
  float2* yrow = yp + t * MK;
#pragma unroll
  for (int rep = 0; rep < 4; ++rep) {
    int m = lane + rep * 64;
    if (m < MK) {
      float a = syy[wid][m];
      float b = syy[wid][m < MK - 1 ? m + 1 : MK - 1];
      yrow[m] = make_float2(a, b);
    }
  }
  const float* ld = logderiv + t * MK;
  float2* drow = dp + t * MK;
#pragma unroll
  for (int rep = 0; rep < 4; ++rep) {
    int m = lane + rep * 64;
    if (m < MK) {
      float a = __expf(ld[m]);
      float b = __expf(ld[m < MK - 1 ? m + 1 : MK - 1]);
      drow[m] = make_float2(a, b);
    }
  }
}

// ---------------------------------------------------------------------------
// Kernel 3: fused gather -> d0 = x.Q -> spline -> out = x + (y-d0).Q^T.
// One thread = one sample (for a fixed patch). blockIdx % 64 = patch so all
// workgroups of a patch share an XCD (L2 locality for yp/dp/xx).
// Q is read via wave-uniform (scalar) loads; only xx lives in LDS.
// ---------------------------------------------------------------------------
__global__ __launch_bounds__(256, 2) void main_kernel(
    const float* __restrict__ data, const float* __restrict__ Qws,
    const float* __restrict__ xxws, const float2* __restrict__ yp,
    const float2* __restrict__ dp, float* __restrict__ out,
    float* __restrict__ partial) {
  const int tid = threadIdx.x;
  const int k = blockIdx.x & 63;
  const int w = blockIdx.x >> 6;
  __shared__ float sxx[NS * MK];
  __shared__ int spo[24];                    // float offsets of the 24 float2 pairs
  if (tid < 24) {
    int p = tid, kh = p / 6, g = p % 6;
    int nh = k >> 3, nw = k & 7;
    int rr = (nh * 4 + kh + 2) & 31;
    int off;
    if (nw < 7) off = rr * 96 + 12 * nw + 6 + 2 * g;
    else        off = rr * 96 + (g < 3 ? 90 + 2 * g : 2 * (g - 3));  // wrap: cols 30,31 then 0,1
    spo[p] = off;
  }
  for (int i = tid; i < NS * MK; i += 256) sxx[i] = xxws[k * (NS * MK) + i];
  __syncthreads();

  const float* Qk = Qws + k * NS * NS;
  const float2* ypk = yp + k * NS * MK;
  const float2* dpk = dp + k * NS * MK;

#pragma unroll 1
  for (int rep = 0; rep < 2; ++rep) {
    const int n = w * 512 + rep * 256 + tid;
    const float* drow = data + (size_t)n * NDIM;
    float x[NS];
#pragma unroll
    for (int p = 0; p < 24; ++p) {
      float2 v2 = *(const float2*)(drow + spo[p]);
      x[2 * p] = v2.x; x[2 * p + 1] = v2.y;
    }
    // --- phase A: d0 = x . Q  (Q reads are wave-uniform -> s_load) ---
    float acc[NS];
#pragma unroll
    for (int j = 0; j < NS; ++j) acc[j] = 0.f;
#pragma unroll
    for (int d = 0; d < NS; ++d) {
      float xd = x[d];
      const float* qrow = Qk + d * NS;
#pragma unroll
      for (int j = 0; j < NS; ++j) acc[j] = fmaf(xd, qrow[j], acc[j]);
    }
    // --- phase B: rational-quadratic spline per transform ---
    float logsum = 0.f;
#pragma unroll
    for (int j = 0; j < NS; ++j) {
      float v = acc[j];
      const float* xr = sxx + j * MK;
      int pos = 0;                            // = searchsorted(xx, v, 'left')
#pragma unroll
      for (int s = 128; s >= 1; s >>= 1) {
        int cand = pos + s;
        int idx = (cand < MK ? cand : MK) - 1;
        float xv = xr[idx];
        pos = (cand <= MK && xv < v) ? cand : pos;
      }
      int kk = pos - 1;
      kk = kk < 0 ? 0 : (kk > MK - 2 ? MK - 2 : kk);
      float xK = xr[kk], xK1 = xr[kk + 1];
      float2 ypr = ypk[j * MK + kk];
      float2 dpr = dpk[j * MK + kk];
      float yK = ypr.x, yK1 = ypr.y, dK = dpr.x, dK1 = dpr.y;
      float rdx = rcp_fast(xK1 - xK);
      float xi = (v - xK) * rdx;
      xi = fminf(fmaxf(xi, 0.f), 1.f);
      float dy = yK1 - yK;
      float s_ = dy * rdx;
      float omxi = 1.f - xi;
      float xi1 = xi * omxi;
      float xi2 = xi * xi;
      float denom = fmaf(dK1 + dK - 2.f * s_, xi1, s_);
      float rden = rcp_fast(denom);
      float y_in = fmaf(dy * fmaf(s_, xi2, dK * xi1), rden, yK);
      float d_in = s_ * s_ * (dK1 * xi2 + 2.f * s_ * xi1 + dK * omxi * omxi) * (rden * rden);
      float yv, dd;
      if (pos == 0)       { yv = fmaf(dK,  v - xK,  yK);  dd = dK;  }
      else if (pos == MK) { yv = fmaf(dK1, v - xK1, yK1); dd = dK1; }
      else                { yv = y_in; dd = d_in; }
      logsum += __logf(dd);
      acc[j] = yv - v;                        // e = y - d0
    }
    partial[k * N_SAMP + n] = logsum;
    // --- phase C: out = x + e . Q^T, scatter ---
    float* orow = out + (size_t)n * NDIM;
#pragma unroll
    for (int p = 0; p < 24; ++p) {
      float r0 = x[2 * p], r1 = x[2 * p + 1];
      const float* q0 = Qk + (2 * p) * NS;
      const float* q1 = Qk + (2 * p + 1) * NS;
#pragma unroll
      for (int j = 0; j < NS; ++j) {
        float ej = acc[j];
        r0 = fmaf(ej, q0[j], r0);
        r1 = fmaf(ej, q1[j], r1);
      }
      *(float2*)(orow + spo[p]) = make_float2(r0, r1);
    }
  }
}

// ---------------------------------------------------------------------------
// Kernel 4: logj[n] = sum_k partial[k][n]
// ---------------------------------------------------------------------------
__global__ __launch_bounds__(256) void reduce_kernel(const float* __restrict__ partial,
                                                     float* __restrict__ logj) {
  int n = blockIdx.x * 256 + threadIdx.x;
  float s = 0.f;
#pragma unroll
  for (int k = 0; k < NK; ++k) s += partial[k * N_SAMP + n];
  logj[n] = s;
}

extern "C" void kernel_launch(void* const* d_in, const int* in_sizes, int n_in,
                              void* d_out, int out_size, void* d_ws, size_t ws_size,
                              hipStream_t stream) {
  const float* data     = (const float*)d_in[0];
  const float* Araw     = (const float*)d_in[1];
  const float* x0       = (const float*)d_in[2];
  const float* logdx    = (const float*)d_in[3];
  const float* y0       = (const float*)d_in[4];
  const float* logdy    = (const float*)d_in[5];
  const float* logderiv = (const float*)d_in[6];
  float* out = (float*)d_out;

  float* ws = (float*)d_ws;
  float*  Qws     = ws;                                  // 64*48*48   = 147456 f
  float*  xxws    = Qws + 64 * 48 * 48;                  // 3072*200   = 614400 f
  float2* yp      = (float2*)(xxws + 3072 * 200);        // 3072*200 float2
  float2* dp      = yp + 3072 * 200;                     // 3072*200 float2
  float*  partial = (float*)(dp + 3072 * 200);           // 64*8192    = 524288 f
  // total ws use: 3,743,744 floats = 14.3 MiB

  qr_kernel<<<64, 64, 0, stream>>>(Araw, Qws);
  knots_kernel<<<768, 256, 0, stream>>>(x0, logdx, y0, logdy, logderiv, xxws, yp, dp);
  main_kernel<<<1024, 256, 0, stream>>>(data, Qws, xxws, yp, dp, out, partial);
  reduce_kernel<<<32, 256, 0, stream>>>(partial, out + (size_t)N_SAMP * NDIM);
}

// Round 2
// 788.123 us; speedup vs baseline: 2.4776x; 2.4776x over previous
//
#include <hip/hip_runtime.h>

#define NSMP  8192
#define CHUNK 2048
#define NDIM  3072
#define NK    64
#define NS    48
#define MK    200   // knots per transform
#define GB    256   // lookup-grid buckets

__device__ __forceinline__ float rcp_fast(float x) { return __builtin_amdgcn_rcpf(x); }

// ---------------------------------------------------------------------------
// Kernel 1: 64 independent 48x48 QR factorizations (modified Gram-Schmidt).
// Lane j owns column j. MGS yields positive-diag R = reference's sign-fixed Q.
// ---------------------------------------------------------------------------
__global__ __launch_bounds__(64) void qr_kernel(const float* __restrict__ Araw,
                                                float* __restrict__ Qws) {
  const int k = blockIdx.x;
  const int lane = threadIdx.x;
  const float* Ak = Araw + k * NS * NS;
  float col[NS];
#pragma unroll
  for (int r = 0; r < NS; ++r)
    col[r] = (lane < NS) ? Ak[r * NS + lane] : 0.f;

  for (int j = 0; j < NS; ++j) {
    float q[NS];
#pragma unroll
    for (int r = 0; r < NS; ++r)
      q[r] = __int_as_float(__builtin_amdgcn_readlane(__float_as_int(col[r]), j));
    float n0 = 0.f, n1 = 0.f, n2 = 0.f, n3 = 0.f;
#pragma unroll
    for (int r = 0; r < NS; r += 4) {
      n0 = fmaf(q[r+0], q[r+0], n0); n1 = fmaf(q[r+1], q[r+1], n1);
      n2 = fmaf(q[r+2], q[r+2], n2); n3 = fmaf(q[r+3], q[r+3], n3);
    }
    float rinv = 1.0f / sqrtf((n0 + n1) + (n2 + n3));
#pragma unroll
    for (int r = 0; r < NS; ++r) q[r] *= rinv;
    if (lane == j) {
#pragma unroll
      for (int r = 0; r < NS; ++r) col[r] = q[r];
    } else if (lane > j && lane < NS) {
      float d0 = 0.f, d1 = 0.f, d2 = 0.f, d3 = 0.f;
#pragma unroll
      for (int r = 0; r < NS; r += 4) {
        d0 = fmaf(q[r+0], col[r+0], d0); d1 = fmaf(q[r+1], col[r+1], d1);
        d2 = fmaf(q[r+2], col[r+2], d2); d3 = fmaf(q[r+3], col[r+3], d3);
      }
      float dt = (d0 + d1) + (d2 + d3);
#pragma unroll
      for (int r = 0; r < NS; ++r) col[r] = fmaf(-dt, q[r], col[r]);
    }
  }
  if (lane < NS) {
    float* Qk = Qws + k * NS * NS;           // row-major Q[d][j]
#pragma unroll
    for (int r = 0; r < NS; ++r) Qk[r * NS + lane] = col[r];
  }
}

// ---------------------------------------------------------------------------
// Kernel 2: knot tables. One wave per transform row t.
//  xxg[t][0..199]        knot x positions
//  ydk[t][k] float4      (yy[k], yy[k+1], delta[k], delta[k+1]) for k<199
//  edge[t*2+{0,1}]       (xx0,yy0,del0,scale), (xxM,yyM,delM,0)
//  gridb[t][g] uint8     start interval for bucket g (G=256 over [xx0,xxM])
// ---------------------------------------------------------------------------
__global__ __launch_bounds__(256) void knots_kernel(
    const float* __restrict__ x0, const float* __restrict__ logdx,
    const float* __restrict__ y0, const float* __restrict__ logdy,
    const float* __restrict__ logderiv,
    float* __restrict__ xxg, float4* __restrict__ ydk,
    float4* __restrict__ edge, unsigned char* __restrict__ gridb) {
  const int wid = threadIdx.x >> 6, lane = threadIdx.x & 63;
  const int t = blockIdx.x * 4 + wid;
  __shared__ float sxx[4][MK], syy[4][MK], sdel[4][MK];

  // ---- xx scan (store global + LDS) ----
  {
    const float* row = logdx + t * (MK - 1);
    int i0 = lane * 4;
    float e0 = (i0 + 0 < MK - 1) ? __expf(row[i0 + 0]) : 0.f;
    float e1 = (i0 + 1 < MK - 1) ? __expf(row[i0 + 1]) : 0.f;
    float e2 = (i0 + 2 < MK - 1) ? __expf(row[i0 + 2]) : 0.f;
    float e3 = (i0 + 3 < MK - 1) ? __expf(row[i0 + 3]) : 0.f;
    float p0 = e0, p1 = p0 + e1, p2 = p1 + e2, p3 = p2 + e3;
    float incl = p3;
#pragma unroll
    for (int off = 1; off < 64; off <<= 1) {
      float u = __shfl_up(incl, off, 64);
      if (lane >= off) incl += u;
    }
    float xv = x0[t];
    float base = xv + (incl - p3);
    float* xrow = xxg + t * MK;
    if (lane == 0) { xrow[0] = xv; sxx[wid][0] = xv; }
    if (i0 + 0 < MK - 1) { xrow[1+i0+0] = base + p0; sxx[wid][1+i0+0] = base + p0; }
    if (i0 + 1 < MK - 1) { xrow[1+i0+1] = base + p1; sxx[wid][1+i0+1] = base + p1; }
    if (i0 + 2 < MK - 1) { xrow[1+i0+2] = base + p2; sxx[wid][1+i0+2] = base + p2; }
    if (i0 + 3 < MK - 1) { xrow[1+i0+3] = base + p3; sxx[wid][1+i0+3] = base + p3; }
  }
  // ---- yy scan (LDS only) ----
  {
    const float* row = logdy + t * (MK - 1);
    int i0 = lane * 4;
    float e0 = (i0 + 0 < MK - 1) ? __expf(row[i0 + 0]) : 0.f;
    float e1 = (i0 + 1 < MK - 1) ? __expf(row[i0 + 1]) : 0.f;
    float e2 = (i0 + 2 < MK - 1) ? __expf(row[i0 + 2]) : 0.f;
    float e3 = (i0 + 3 < MK - 1) ? __expf(row[i0 + 3]) : 0.f;
    float p0 = e0, p1 = p0 + e1, p2 = p1 + e2, p3 = p2 + e3;
    float incl = p3;
#pragma unroll
    for (int off = 1; off < 64; off <<= 1) {
      float u = __shfl_up(incl, off, 64);
      if (lane >= off) incl += u;
    }
    float yv = y0[t];
    float base = yv + (incl - p3);
    if (lane == 0) syy[wid][0] = yv;
    if (i0 + 0 < MK - 1) syy[wid][1+i0+0] = base + p0;
    if (i0 + 1 < MK - 1) syy[wid][1+i0+1] = base + p1;
    if (i0 + 2 < MK - 1) syy[wid][1+i0+2] = base + p2;
    if (i0 + 3 < MK - 1) syy[wid][1+i0+3] = base + p3;
  }
  // ---- delta ----
  {
    const float* ld = logderiv + t * MK;
#pragma unroll
    for (int rep = 0; rep < 4; ++rep) {
      int m = lane + rep * 64;
      if (m < MK) sdel[wid][m] = __expf(ld[m]);
    }
  }
  __syncthreads();

  // ---- ydk records ----
#pragma unroll
  for (int rep = 0; rep < 4; ++rep) {
    int kk = lane + rep * 64;
    if (kk < MK - 1)
      ydk[t * (MK-1) + kk] = make_float4(syy[wid][kk], syy[wid][kk+1],
                                         sdel[wid][kk], sdel[wid][kk+1]);
  }
  // ---- edge params ----
  float xx0v = sxx[wid][0], xxMv = sxx[wid][MK-1];
  if (lane == 0) {
    float scale = (float)GB / (xxMv - xx0v);
    edge[t*2+0] = make_float4(xx0v, syy[wid][0],    sdel[wid][0],    scale);
    edge[t*2+1] = make_float4(xxMv, syy[wid][MK-1], sdel[wid][MK-1], 0.f);
  }
  // ---- bucket grid ----
  float bw = (xxMv - xx0v) * (1.f / (float)GB);
#pragma unroll
  for (int i = 0; i < 4; ++i) {
    int g = lane * 4 + i;
    float L = xx0v + (float)g * bw;
    int p = 0;
#pragma unroll
    for (int st = 128; st >= 1; st >>= 1) {
      int cand = p + st;
      if (cand < MK && sxx[wid][cand] < L) p = cand;
    }
    gridb[t * GB + g] = (unsigned char)(p > MK-2 ? MK-2 : p);
  }
}

// ---------------------------------------------------------------------------
// Kernel M1: d0 = x . Q per (sample, patch). Block = row-block nh x 32 samples
// x 8 patches co-resident (full-line consumption). Writes d0 [k][j][n] coalesced.
// ---------------------------------------------------------------------------
__global__ __launch_bounds__(256) void m1_project(const float* __restrict__ data,
                                                  const float* __restrict__ Qws,
                                                  float* __restrict__ d0ws,
                                                  int chunk_base) {
  const int tid = threadIdx.x;
  const int s = tid & 31, nw = tid >> 5;
  const int nh = blockIdx.x & 7, tile = blockIdx.x >> 3;
  const int nl = tile * 32 + s;
  const int n = chunk_base + nl;
  const int k = nh * 8 + nw;
  const float* Qk = Qws + k * NS * NS;
  const float* drow = data + (size_t)n * NDIM;
  float acc[NS];
#pragma unroll
  for (int j = 0; j < NS; ++j) acc[j] = 0.f;
#pragma unroll
  for (int kh = 0; kh < 4; ++kh) {
    const int rr = (nh * 4 + kh + 2) & 31;
    const float* seg = drow + rr * 96;
    const int col0 = 12 * nw + 6;
#pragma unroll
    for (int jj = 0; jj < 6; ++jj) {
      int c = col0 + 2 * jj; c -= (c >= 96) ? 96 : 0;
      float2 x2 = *(const float2*)(seg + c);
      const float4* qa = (const float4*)(Qk + (kh * 12 + 2*jj    ) * NS);
      const float4* qb = (const float4*)(Qk + (kh * 12 + 2*jj + 1) * NS);
#pragma unroll
      for (int q = 0; q < 12; ++q) {
        float4 a = qa[q], b = qb[q];
        acc[4*q+0] = fmaf(x2.y, b.x, fmaf(x2.x, a.x, acc[4*q+0]));
        acc[4*q+1] = fmaf(x2.y, b.y, fmaf(x2.x, a.y, acc[4*q+1]));
        acc[4*q+2] = fmaf(x2.y, b.z, fmaf(x2.x, a.z, acc[4*q+2]));
        acc[4*q+3] = fmaf(x2.y, b.w, fmaf(x2.x, a.w, acc[4*q+3]));
      }
    }
  }
  float* dst = d0ws + (size_t)k * NS * CHUNK + nl;
#pragma unroll
  for (int j = 0; j < NS; ++j) dst[j * CHUNK] = acc[j];
}

// ---------------------------------------------------------------------------
// Kernel M2: spline. Block = one patch x 256 samples. Bucket-grid search in
// LDS + one float4 knot-record gather (L2-hot). In-place e = y - d0.
// ---------------------------------------------------------------------------
__global__ __launch_bounds__(256) void m2_spline(
    float* __restrict__ d0e, const float* __restrict__ xxg,
    const unsigned char* __restrict__ gridb, const float4* __restrict__ edge,
    const float4* __restrict__ ydk, float* __restrict__ partial, int chunk_base) {
  const int tid = threadIdx.x;
  const int k = blockIdx.x & 63, tile = blockIdx.x >> 6;
  const int nl = tile * 256 + tid;
  __shared__ float sxx2[NS * MK];
  __shared__ unsigned int sgrid_u[NS * GB / 4];
  __shared__ float4 sedge[NS * 2];
  for (int i = tid; i < NS * MK; i += 256) sxx2[i] = xxg[k * NS * MK + i];
  const unsigned int* gsrc = (const unsigned int*)(gridb + (size_t)k * NS * GB);
  for (int i = tid; i < NS * GB / 4; i += 256) sgrid_u[i] = gsrc[i];
  if (tid < NS * 2) sedge[tid] = edge[k * NS * 2 + tid];
  __syncthreads();
  const unsigned char* sgrid = (const unsigned char*)sgrid_u;

  float logsum = 0.f;
#pragma unroll 4
  for (int j = 0; j < NS; ++j) {
    const int base = (k * NS + j) * CHUNK + nl;
    float v = d0e[base];
    float4 e0 = sedge[2*j], e1 = sedge[2*j+1];
    const float* xr = sxx2 + j * MK;
    int g = (int)((v - e0.x) * e0.w);
    g = g < 0 ? 0 : (g > GB-1 ? GB-1 : g);
    int kk = sgrid[j * GB + g];
#pragma unroll
    for (int it = 0; it < 3; ++it) kk += (kk < MK-2 && xr[kk+1] < v) ? 1 : 0;
    float xK = xr[kk], xK1 = xr[kk+1];
    float4 r = ydk[(k * NS + j) * (MK-1) + kk];   // (yK,yK1,dK,dK1)
    float rdx = rcp_fast(xK1 - xK);
    float xi = (v - xK) * rdx;
    xi = fminf(fmaxf(xi, 0.f), 1.f);
    float dy = r.y - r.x;
    float s_ = dy * rdx;
    float omxi = 1.f - xi, xi1 = xi * omxi, xi2 = xi * xi;
    float denom = fmaf(r.z + r.w - 2.f * s_, xi1, s_);
    float rden = rcp_fast(denom);
    float y_in = fmaf(dy * fmaf(s_, xi2, r.z * xi1), rden, r.x);
    float d_in = s_ * s_ * (r.w * xi2 + 2.f * s_ * xi1 + r.z * omxi * omxi) * (rden * rden);
    bool below = v <= e0.x, above = v > e1.x;
    float yv = below ? fmaf(e0.z, v - e0.x, e0.y)
             : (above ? fmaf(e1.z, v - e1.x, e1.y) : y_in);
    float dd = below ? e0.z : (above ? e1.z : d_in);
    logsum += __logf(dd);
    d0e[base] = yv - v;                           // e = y - d0, in place
  }
  partial[k * NSMP + chunk_base + nl] = logsum;
}

// ---------------------------------------------------------------------------
// Kernel M3: out = x + e . Q^T. Same block layout as M1; the 8 co-resident
// patches write complementary parts of each line -> L2 write-combines.
// ---------------------------------------------------------------------------
__global__ __launch_bounds__(256) void m3_output(const float* __restrict__ data,
                                                 const float* __restrict__ Qws,
                                                 const float* __restrict__ ews,
                                                 float* __restrict__ out,
                                                 int chunk_base) {
  const int tid = threadIdx.x;
  const int s = tid & 31, nw = tid >> 5;
  const int nh = blockIdx.x & 7, tile = blockIdx.x >> 3;
  const int nl = tile * 32 + s;
  const int n = chunk_base + nl;
  const int k = nh * 8 + nw;
  const float* Qk = Qws + k * NS * NS;
  float e[NS];
  const float* src = ews + (size_t)k * NS * CHUNK + nl;
#pragma unroll
  for (int j = 0; j < NS; ++j) e[j] = src[j * CHUNK];
  const float* drow = data + (size_t)n * NDIM;
  float* orow = out + (size_t)n * NDIM;
#pragma unroll
  for (int kh = 0; kh < 4; ++kh) {
    const int rr = (nh * 4 + kh + 2) & 31;
    const int segoff = rr * 96;
    const int col0 = 12 * nw + 6;
#pragma unroll
    for (int jj = 0; jj < 6; ++jj) {
      int c = col0 + 2 * jj; c -= (c >= 96) ? 96 : 0;
      const float4* qa = (const float4*)(Qk + (kh * 12 + 2*jj    ) * NS);
      const float4* qb = (const float4*)(Qk + (kh * 12 + 2*jj + 1) * NS);
      float r0 = 0.f, r1 = 0.f;
#pragma unroll
      for (int q = 0; q < 12; ++q) {
        float4 a = qa[q], b = qb[q];
        r0 = fmaf(e[4*q+0], a.x, fmaf(e[4*q+1], a.y, fmaf(e[4*q+2], a.z, fmaf(e[4*q+3], a.w, r0))));
        r1 = fmaf(e[4*q+0], b.x, fmaf(e[4*q+1], b.y, fmaf(e[4*q+2], b.z, fmaf(e[4*q+3], b.w, r1))));
      }
      float2 x2 = *(const float2*)(drow + segoff + c);
      *(float2*)(orow + segoff + c) = make_float2(x2.x + r0, x2.y + r1);
    }
  }
}

// ---------------------------------------------------------------------------
// Kernel 4: logj[n] = sum_k partial[k][n]
// ---------------------------------------------------------------------------
__global__ __launch_bounds__(256) void reduce_kernel(const float* __restrict__ partial,
                                                     float* __restrict__ logj) {
  int n = blockIdx.x * 256 + threadIdx.x;
  float s = 0.f;
#pragma unroll
  for (int k = 0; k < NK; ++k) s += partial[k * NSMP + n];
  logj[n] = s;
}

extern "C" void kernel_launch(void* const* d_in, const int* in_sizes, int n_in,
                              void* d_out, int out_size, void* d_ws, size_t ws_size,
                              hipStream_t stream) {
  const float* data     = (const float*)d_in[0];
  const float* Araw     = (const float*)d_in[1];
  const float* x0       = (const float*)d_in[2];
  const float* logdx    = (const float*)d_in[3];
  const float* y0       = (const float*)d_in[4];
  const float* logdy    = (const float*)d_in[5];
  const float* logderiv = (const float*)d_in[6];
  float* out = (float*)d_out;

  float* ws = (float*)d_ws;
  float*         Qws   = ws;                               // 147456 f
  float*         xxg   = Qws  + 64 * NS * NS;              // 614400 f
  float4*        ydk   = (float4*)(xxg + 3072 * MK);       // 3072*199 float4
  float4*        edge  = ydk + 3072 * (MK - 1);            // 3072*2 float4
  unsigned char* gridb = (unsigned char*)(edge + 3072 * 2);// 786432 B
  float*         d0ws  = (float*)(gridb + 3072 * GB);      // 64*48*2048 f
  float*         partial = d0ws + (size_t)NK * NS * CHUNK; // 64*8192 f
  // total ~41 MB

  qr_kernel<<<64, 64, 0, stream>>>(Araw, Qws);
  knots_kernel<<<768, 256, 0, stream>>>(x0, logdx, y0, logdy, logderiv,
                                        xxg, ydk, edge, gridb);
  for (int c = 0; c < 4; ++c) {
    const int base = c * CHUNK;
    m1_project<<<512, 256, 0, stream>>>(data, Qws, d0ws, base);
    m2_spline <<<512, 256, 0, stream>>>(d0ws, xxg, gridb, edge, ydk, partial, base);
    m3_output <<<512, 256, 0, stream>>>(data, Qws, d0ws, out, base);
  }
  reduce_kernel<<<32, 256, 0, stream>>>(partial, out + (size_t)NSMP * NDIM);
}

// Round 3
// 638.796 us; speedup vs baseline: 3.0567x; 1.2338x over previous
//
#include <hip/hip_runtime.h>

#define NSMP  8192
#define CHUNK 2048
#define NDIM  3072
#define NK    64
#define NS    48
#define MK    200   // knots per transform
#define GB    256   // lookup-grid buckets

__device__ __forceinline__ float rcp_fast(float x) { return __builtin_amdgcn_rcpf(x); }

// ---------------------------------------------------------------------------
// Kernel 1: 64 independent 48x48 QR factorizations (modified Gram-Schmidt).
// Lane j owns column j. MGS yields positive-diag R = reference's sign-fixed Q.
// ---------------------------------------------------------------------------
__global__ __launch_bounds__(64) void qr_kernel(const float* __restrict__ Araw,
                                                float* __restrict__ Qws) {
  const int k = blockIdx.x;
  const int lane = threadIdx.x;
  const float* Ak = Araw + k * NS * NS;
  float col[NS];
#pragma unroll
  for (int r = 0; r < NS; ++r)
    col[r] = (lane < NS) ? Ak[r * NS + lane] : 0.f;

  for (int j = 0; j < NS; ++j) {
    float q[NS];
#pragma unroll
    for (int r = 0; r < NS; ++r)
      q[r] = __int_as_float(__builtin_amdgcn_readlane(__float_as_int(col[r]), j));
    float n0 = 0.f, n1 = 0.f, n2 = 0.f, n3 = 0.f;
#pragma unroll
    for (int r = 0; r < NS; r += 4) {
      n0 = fmaf(q[r+0], q[r+0], n0); n1 = fmaf(q[r+1], q[r+1], n1);
      n2 = fmaf(q[r+2], q[r+2], n2); n3 = fmaf(q[r+3], q[r+3], n3);
    }
    float rinv = 1.0f / sqrtf((n0 + n1) + (n2 + n3));
#pragma unroll
    for (int r = 0; r < NS; ++r) q[r] *= rinv;
    if (lane == j) {
#pragma unroll
      for (int r = 0; r < NS; ++r) col[r] = q[r];
    } else if (lane > j && lane < NS) {
      float d0 = 0.f, d1 = 0.f, d2 = 0.f, d3 = 0.f;
#pragma unroll
      for (int r = 0; r < NS; r += 4) {
        d0 = fmaf(q[r+0], col[r+0], d0); d1 = fmaf(q[r+1], col[r+1], d1);
        d2 = fmaf(q[r+2], col[r+2], d2); d3 = fmaf(q[r+3], col[r+3], d3);
      }
      float dt = (d0 + d1) + (d2 + d3);
#pragma unroll
      for (int r = 0; r < NS; ++r) col[r] = fmaf(-dt, q[r], col[r]);
    }
  }
  if (lane < NS) {
    float* Qk = Qws + k * NS * NS;           // row-major Q[d][j]
#pragma unroll
    for (int r = 0; r < NS; ++r) Qk[r * NS + lane] = col[r];
  }
}

// ---------------------------------------------------------------------------
// Kernel 2: knot tables (unchanged from round 2 — validated).
// ---------------------------------------------------------------------------
__global__ __launch_bounds__(256) void knots_kernel(
    const float* __restrict__ x0, const float* __restrict__ logdx,
    const float* __restrict__ y0, const float* __restrict__ logdy,
    const float* __restrict__ logderiv,
    float* __restrict__ xxg, float4* __restrict__ ydk,
    float4* __restrict__ edge, unsigned char* __restrict__ gridb) {
  const int wid = threadIdx.x >> 6, lane = threadIdx.x & 63;
  const int t = blockIdx.x * 4 + wid;
  __shared__ float sxx[4][MK], syy[4][MK], sdel[4][MK];

  {
    const float* row = logdx + t * (MK - 1);
    int i0 = lane * 4;
    float e0 = (i0 + 0 < MK - 1) ? __expf(row[i0 + 0]) : 0.f;
    float e1 = (i0 + 1 < MK - 1) ? __expf(row[i0 + 1]) : 0.f;
    float e2 = (i0 + 2 < MK - 1) ? __expf(row[i0 + 2]) : 0.f;
    float e3 = (i0 + 3 < MK - 1) ? __expf(row[i0 + 3]) : 0.f;
    float p0 = e0, p1 = p0 + e1, p2 = p1 + e2, p3 = p2 + e3;
    float incl = p3;
#pragma unroll
    for (int off = 1; off < 64; off <<= 1) {
      float u = __shfl_up(incl, off, 64);
      if (lane >= off) incl += u;
    }
    float xv = x0[t];
    float base = xv + (incl - p3);
    float* xrow = xxg + t * MK;
    if (lane == 0) { xrow[0] = xv; sxx[wid][0] = xv; }
    if (i0 + 0 < MK - 1) { xrow[1+i0+0] = base + p0; sxx[wid][1+i0+0] = base + p0; }
    if (i0 + 1 < MK - 1) { xrow[1+i0+1] = base + p1; sxx[wid][1+i0+1] = base + p1; }
    if (i0 + 2 < MK - 1) { xrow[1+i0+2] = base + p2; sxx[wid][1+i0+2] = base + p2; }
    if (i0 + 3 < MK - 1) { xrow[1+i0+3] = base + p3; sxx[wid][1+i0+3] = base + p3; }
  }
  {
    const float* row = logdy + t * (MK - 1);
    int i0 = lane * 4;
    float e0 = (i0 + 0 < MK - 1) ? __expf(row[i0 + 0]) : 0.f;
    float e1 = (i0 + 1 < MK - 1) ? __expf(row[i0 + 1]) : 0.f;
    float e2 = (i0 + 2 < MK - 1) ? __expf(row[i0 + 2]) : 0.f;
    float e3 = (i0 + 3 < MK - 1) ? __expf(row[i0 + 3]) : 0.f;
    float p0 = e0, p1 = p0 + e1, p2 = p1 + e2, p3 = p2 + e3;
    float incl = p3;
#pragma unroll
    for (int off = 1; off < 64; off <<= 1) {
      float u = __shfl_up(incl, off, 64);
      if (lane >= off) incl += u;
    }
    float yv = y0[t];
    float base = yv + (incl - p3);
    if (lane == 0) syy[wid][0] = yv;
    if (i0 + 0 < MK - 1) syy[wid][1+i0+0] = base + p0;
    if (i0 + 1 < MK - 1) syy[wid][1+i0+1] = base + p1;
    if (i0 + 2 < MK - 1) syy[wid][1+i0+2] = base + p2;
    if (i0 + 3 < MK - 1) syy[wid][1+i0+3] = base + p3;
  }
  {
    const float* ld = logderiv + t * MK;
#pragma unroll
    for (int rep = 0; rep < 4; ++rep) {
      int m = lane + rep * 64;
      if (m < MK) sdel[wid][m] = __expf(ld[m]);
    }
  }
  __syncthreads();

#pragma unroll
  for (int rep = 0; rep < 4; ++rep) {
    int kk = lane + rep * 64;
    if (kk < MK - 1)
      ydk[t * (MK-1) + kk] = make_float4(syy[wid][kk], syy[wid][kk+1],
                                         sdel[wid][kk], sdel[wid][kk+1]);
  }
  float xx0v = sxx[wid][0], xxMv = sxx[wid][MK-1];
  if (lane == 0) {
    float scale = (float)GB / (xxMv - xx0v);
    edge[t*2+0] = make_float4(xx0v, syy[wid][0],    sdel[wid][0],    scale);
    edge[t*2+1] = make_float4(xxMv, syy[wid][MK-1], sdel[wid][MK-1], 0.f);
  }
  float bw = (xxMv - xx0v) * (1.f / (float)GB);
#pragma unroll
  for (int i = 0; i < 4; ++i) {
    int g = lane * 4 + i;
    float L = xx0v + (float)g * bw;
    int p = 0;
#pragma unroll
    for (int st = 128; st >= 1; st >>= 1) {
      int cand = p + st;
      if (cand < MK && sxx[wid][cand] < L) p = cand;
    }
    gridb[t * GB + g] = (unsigned char)(p > MK-2 ? MK-2 : p);
  }
}

// ---------------------------------------------------------------------------
// Kernel G: LDS transpose  data[n][dim] -> Xg[k][d][n]  (fully coalesced).
// Block = (32 samples, one image-row rr). rr -> (nh, kh); cols -> (nw, dd).
// ---------------------------------------------------------------------------
__global__ __launch_bounds__(256) void gather_kernel(const float* __restrict__ data,
                                                     float* __restrict__ Xg,
                                                     int chunk_base) {
  const int tid = threadIdx.x;
  const int rr = blockIdx.x & 31, tile = blockIdx.x >> 5;
  const int q = (rr + 30) & 31;           // (rr-2) mod 32
  const int nh = q >> 2, kh = q & 3;
  const int n0 = tile * 32;
  __shared__ float sd[32][97];
#pragma unroll
  for (int it = 0; it < 3; ++it) {
    int i = tid + it * 256;               // 768 float4s = 32 samples * 24
    int s = i / 24, f4 = i % 24;
    float4 v = *(const float4*)(data + (size_t)(chunk_base + n0 + s) * NDIM + rr * 96 + f4 * 4);
    sd[s][f4*4+0] = v.x; sd[s][f4*4+1] = v.y; sd[s][f4*4+2] = v.z; sd[s][f4*4+3] = v.w;
  }
  __syncthreads();
#pragma unroll
  for (int it = 0; it < 12; ++it) {
    int o = tid + it * 256;               // 3072 = 96 cols * 32 samples
    int s = o & 31, p = o >> 5;
    int nw = p / 12, dd = p % 12;
    int c = 12 * nw + 6 + dd; c -= (c >= 96) ? 96 : 0;
    int k = nh * 8 + nw, d = kh * 12 + dd;
    Xg[((size_t)(k * NS + d)) * CHUNK + n0 + s] = sd[s][c];
  }
}

// ---------------------------------------------------------------------------
// Kernel C: per-patch core. Block = (patch k, 256 samples). Everything
// coalesced in n; Q is block-uniform -> scalar loads. In-place Xg -> R.
// ---------------------------------------------------------------------------
__global__ __launch_bounds__(256, 3) void core_kernel(
    float* __restrict__ Xg, const float* __restrict__ Qws,
    const float* __restrict__ xxg, const unsigned char* __restrict__ gridb,
    const float4* __restrict__ edge, const float4* __restrict__ ydk,
    float* __restrict__ partial, int chunk_base) {
  const int tid = threadIdx.x;
  const int k = blockIdx.x & 63, tile = blockIdx.x >> 6;
  const int nl = tile * 256 + tid;
  __shared__ float sxx[NS * MK];
  __shared__ unsigned int sgrid_u[NS * GB / 4];
  __shared__ float4 sedge[NS * 2];
  for (int i = tid; i < NS * MK; i += 256) sxx[i] = xxg[k * NS * MK + i];
  const unsigned int* gsrc = (const unsigned int*)(gridb + (size_t)k * NS * GB);
  for (int i = tid; i < NS * GB / 4; i += 256) sgrid_u[i] = gsrc[i];
  if (tid < NS * 2) sedge[tid] = edge[k * NS * 2 + tid];
  __syncthreads();
  const unsigned char* sgrid = (const unsigned char*)sgrid_u;

  float* Xp = Xg + (size_t)k * NS * CHUNK + nl;
  const float* Qk = Qws + k * NS * NS;

  // --- phase A: d0 = x . Q (coalesced x loads, scalar Q) ---
  float acc[NS];
#pragma unroll
  for (int j = 0; j < NS; ++j) acc[j] = 0.f;
#pragma unroll 4
  for (int d = 0; d < NS; ++d) {
    float xd = Xp[(size_t)d * CHUNK];
    const float* qrow = Qk + d * NS;
#pragma unroll
    for (int j = 0; j < NS; ++j) acc[j] = fmaf(xd, qrow[j], acc[j]);
  }
  // --- phase B: rational-quadratic spline, e = y - d0 (in acc) ---
  float logsum = 0.f;
#pragma unroll 4
  for (int j = 0; j < NS; ++j) {
    float v = acc[j];
    float4 e0 = sedge[2*j], e1 = sedge[2*j+1];
    const float* xr = sxx + j * MK;
    int g = (int)((v - e0.x) * e0.w);
    g = g < 0 ? 0 : (g > GB-1 ? GB-1 : g);
    int kk = sgrid[j * GB + g];
#pragma unroll
    for (int it = 0; it < 3; ++it) kk += (kk < MK-2 && xr[kk+1] < v) ? 1 : 0;
    float xK = xr[kk], xK1 = xr[kk+1];
    float4 r = ydk[(k * NS + j) * (MK-1) + kk];   // (yK,yK1,dK,dK1)
    float rdx = rcp_fast(xK1 - xK);
    float xi = (v - xK) * rdx;
    xi = fminf(fmaxf(xi, 0.f), 1.f);
    float dy = r.y - r.x;
    float s_ = dy * rdx;
    float omxi = 1.f - xi, xi1 = xi * omxi, xi2 = xi * xi;
    float denom = fmaf(r.z + r.w - 2.f * s_, xi1, s_);
    float rden = rcp_fast(denom);
    float y_in = fmaf(dy * fmaf(s_, xi2, r.z * xi1), rden, r.x);
    float d_in = s_ * s_ * (r.w * xi2 + 2.f * s_ * xi1 + r.z * omxi * omxi) * (rden * rden);
    bool below = v <= e0.x, above = v > e1.x;
    float yv = below ? fmaf(e0.z, v - e0.x, e0.y)
             : (above ? fmaf(e1.z, v - e1.x, e1.y) : y_in);
    float dd = below ? e0.z : (above ? e1.z : d_in);
    logsum += __logf(dd);
    acc[j] = yv - v;                              // e = y - d0
  }
  partial[k * NSMP + chunk_base + nl] = logsum;
  // --- phase C: R[d] = e . Q[d][:]  (in-place, per-thread column) ---
#pragma unroll 2
  for (int d = 0; d < NS; ++d) {
    const float* qrow = Qk + d * NS;
    float r0 = 0.f, r1 = 0.f, r2 = 0.f, r3 = 0.f;
#pragma unroll
    for (int j = 0; j < NS; j += 4) {
      r0 = fmaf(acc[j+0], qrow[j+0], r0);
      r1 = fmaf(acc[j+1], qrow[j+1], r1);
      r2 = fmaf(acc[j+2], qrow[j+2], r2);
      r3 = fmaf(acc[j+3], qrow[j+3], r3);
    }
    Xp[(size_t)d * CHUNK] = (r0 + r1) + (r2 + r3);
  }
}

// ---------------------------------------------------------------------------
// Kernel S: reverse transpose + add:  out[n][dim] = data[n][dim] + R[k][d][n].
// ---------------------------------------------------------------------------
__global__ __launch_bounds__(256) void scatter_kernel(const float* __restrict__ data,
                                                      const float* __restrict__ R,
                                                      float* __restrict__ out,
                                                      int chunk_base) {
  const int tid = threadIdx.x;
  const int rr = blockIdx.x & 31, tile = blockIdx.x >> 5;
  const int q = (rr + 30) & 31;
  const int nh = q >> 2, kh = q & 3;
  const int n0 = tile * 32;
  __shared__ float sd[32][97];
#pragma unroll
  for (int it = 0; it < 12; ++it) {
    int o = tid + it * 256;
    int s = o & 31, p = o >> 5;
    int nw = p / 12, dd = p % 12;
    int c = 12 * nw + 6 + dd; c -= (c >= 96) ? 96 : 0;
    int k = nh * 8 + nw, d = kh * 12 + dd;
    sd[s][c] = R[((size_t)(k * NS + d)) * CHUNK + n0 + s];
  }
  __syncthreads();
#pragma unroll
  for (int it = 0; it < 3; ++it) {
    int i = tid + it * 256;
    int s = i / 24, f4 = i % 24;
    size_t off = (size_t)(chunk_base + n0 + s) * NDIM + rr * 96 + f4 * 4;
    float4 v = *(const float4*)(data + off);
    v.x += sd[s][f4*4+0]; v.y += sd[s][f4*4+1];
    v.z += sd[s][f4*4+2]; v.w += sd[s][f4*4+3];
    *(float4*)(out + off) = v;
  }
}

// ---------------------------------------------------------------------------
// Kernel 4: logj[n] = sum_k partial[k][n]
// ---------------------------------------------------------------------------
__global__ __launch_bounds__(256) void reduce_kernel(const float* __restrict__ partial,
                                                     float* __restrict__ logj) {
  int n = blockIdx.x * 256 + threadIdx.x;
  float s = 0.f;
#pragma unroll
  for (int k = 0; k < NK; ++k) s += partial[k * NSMP + n];
  logj[n] = s;
}

extern "C" void kernel_launch(void* const* d_in, const int* in_sizes, int n_in,
                              void* d_out, int out_size, void* d_ws, size_t ws_size,
                              hipStream_t stream) {
  const float* data     = (const float*)d_in[0];
  const float* Araw     = (const float*)d_in[1];
  const float* x0       = (const float*)d_in[2];
  const float* logdx    = (const float*)d_in[3];
  const float* y0       = (const float*)d_in[4];
  const float* logdy    = (const float*)d_in[5];
  const float* logderiv = (const float*)d_in[6];
  float* out = (float*)d_out;

  float* ws = (float*)d_ws;
  float*         Qws   = ws;                                // 147456 f
  float*         xxg   = Qws  + 64 * NS * NS;               // 614400 f
  float4*        ydk   = (float4*)(xxg + 3072 * MK);        // 3072*199 float4
  float4*        edge  = ydk + 3072 * (MK - 1);             // 3072*2 float4
  unsigned char* gridb = (unsigned char*)(edge + 3072 * 2); // 786432 B
  float*         Xg    = (float*)(gridb + 3072 * GB);       // 64*48*2048 f (in-place R)
  float*         partial = Xg + (size_t)NK * NS * CHUNK;    // 64*8192 f
  // total ~41 MB

  qr_kernel<<<64, 64, 0, stream>>>(Araw, Qws);
  knots_kernel<<<768, 256, 0, stream>>>(x0, logdx, y0, logdy, logderiv,
                                        xxg, ydk, edge, gridb);
  for (int c = 0; c < 4; ++c) {
    const int base = c * CHUNK;
    gather_kernel <<<2048, 256, 0, stream>>>(data, Xg, base);
    core_kernel   <<< 512, 256, 0, stream>>>(Xg, Qws, xxg, gridb, edge, ydk, partial, base);
    scatter_kernel<<<2048, 256, 0, stream>>>(data, Xg, out, base);
  }
  reduce_kernel<<<32, 256, 0, stream>>>(partial, out + (size_t)NSMP * NDIM);
}

// Round 4
// 546.084 us; speedup vs baseline: 3.5757x; 1.1698x over previous
//
#include <hip/hip_runtime.h>

#define NSMP  8192
#define NDIM  3072
#define NK    64
#define NS    48
#define MK    200   // knots per transform
#define GB    256   // lookup-grid buckets

__device__ __forceinline__ float rcp_fast(float x) { return __builtin_amdgcn_rcpf(x); }
__device__ __forceinline__ int imin(int a, int b) { return a < b ? a : b; }

// ---------------------------------------------------------------------------
// Kernel 1: 64 independent 48x48 QR factorizations (modified Gram-Schmidt).
// ---------------------------------------------------------------------------
__global__ __launch_bounds__(64) void qr_kernel(const float* __restrict__ Araw,
                                                float* __restrict__ Qws) {
  const int k = blockIdx.x;
  const int lane = threadIdx.x;
  const float* Ak = Araw + k * NS * NS;
  float col[NS];
#pragma unroll
  for (int r = 0; r < NS; ++r)
    col[r] = (lane < NS) ? Ak[r * NS + lane] : 0.f;

  for (int j = 0; j < NS; ++j) {
    float q[NS];
#pragma unroll
    for (int r = 0; r < NS; ++r)
      q[r] = __int_as_float(__builtin_amdgcn_readlane(__float_as_int(col[r]), j));
    float n0 = 0.f, n1 = 0.f, n2 = 0.f, n3 = 0.f;
#pragma unroll
    for (int r = 0; r < NS; r += 4) {
      n0 = fmaf(q[r+0], q[r+0], n0); n1 = fmaf(q[r+1], q[r+1], n1);
      n2 = fmaf(q[r+2], q[r+2], n2); n3 = fmaf(q[r+3], q[r+3], n3);
    }
    float rinv = 1.0f / sqrtf((n0 + n1) + (n2 + n3));
#pragma unroll
    for (int r = 0; r < NS; ++r) q[r] *= rinv;
    if (lane == j) {
#pragma unroll
      for (int r = 0; r < NS; ++r) col[r] = q[r];
    } else if (lane > j && lane < NS) {
      float d0 = 0.f, d1 = 0.f, d2 = 0.f, d3 = 0.f;
#pragma unroll
      for (int r = 0; r < NS; r += 4) {
        d0 = fmaf(q[r+0], col[r+0], d0); d1 = fmaf(q[r+1], col[r+1], d1);
        d2 = fmaf(q[r+2], col[r+2], d2); d3 = fmaf(q[r+3], col[r+3], d3);
      }
      float dt = (d0 + d1) + (d2 + d3);
#pragma unroll
      for (int r = 0; r < NS; ++r) col[r] = fmaf(-dt, q[r], col[r]);
    }
  }
  if (lane < NS) {
    float* Qk = Qws + k * NS * NS;
#pragma unroll
    for (int r = 0; r < NS; ++r) Qk[r * NS + lane] = col[r];
  }
}

// ---------------------------------------------------------------------------
// Kernel 2: knot tables. One wave per transform row t.
//  xxg[t][0..199]    knot x positions
//  ydk8[t][kk]       2x float4: (xK, 1/dx, yK, dy), (s, dK, dK1, dK+dK1-2s)
//  edge[t*2+{0,1}]   (xx0,yy0,del0,scale), (xxM,yyM,delM,0)
//  gridb[t][g] u8    start interval for bucket g
// ---------------------------------------------------------------------------
__global__ __launch_bounds__(256) void knots_kernel(
    const float* __restrict__ x0, const float* __restrict__ logdx,
    const float* __restrict__ y0, const float* __restrict__ logdy,
    const float* __restrict__ logderiv,
    float* __restrict__ xxg, float4* __restrict__ ydk8,
    float4* __restrict__ edge, unsigned char* __restrict__ gridb) {
  const int wid = threadIdx.x >> 6, lane = threadIdx.x & 63;
  const int t = blockIdx.x * 4 + wid;
  __shared__ float sxx[4][MK], syy[4][MK], sdel[4][MK];

  {
    const float* row = logdx + t * (MK - 1);
    int i0 = lane * 4;
    float e0 = (i0 + 0 < MK - 1) ? __expf(row[i0 + 0]) : 0.f;
    float e1 = (i0 + 1 < MK - 1) ? __expf(row[i0 + 1]) : 0.f;
    float e2 = (i0 + 2 < MK - 1) ? __expf(row[i0 + 2]) : 0.f;
    float e3 = (i0 + 3 < MK - 1) ? __expf(row[i0 + 3]) : 0.f;
    float p0 = e0, p1 = p0 + e1, p2 = p1 + e2, p3 = p2 + e3;
    float incl = p3;
#pragma unroll
    for (int off = 1; off < 64; off <<= 1) {
      float u = __shfl_up(incl, off, 64);
      if (lane >= off) incl += u;
    }
    float xv = x0[t];
    float base = xv + (incl - p3);
    float* xrow = xxg + t * MK;
    if (lane == 0) { xrow[0] = xv; sxx[wid][0] = xv; }
    if (i0 + 0 < MK - 1) { xrow[1+i0+0] = base + p0; sxx[wid][1+i0+0] = base + p0; }
    if (i0 + 1 < MK - 1) { xrow[1+i0+1] = base + p1; sxx[wid][1+i0+1] = base + p1; }
    if (i0 + 2 < MK - 1) { xrow[1+i0+2] = base + p2; sxx[wid][1+i0+2] = base + p2; }
    if (i0 + 3 < MK - 1) { xrow[1+i0+3] = base + p3; sxx[wid][1+i0+3] = base + p3; }
  }
  {
    const float* row = logdy + t * (MK - 1);
    int i0 = lane * 4;
    float e0 = (i0 + 0 < MK - 1) ? __expf(row[i0 + 0]) : 0.f;
    float e1 = (i0 + 1 < MK - 1) ? __expf(row[i0 + 1]) : 0.f;
    float e2 = (i0 + 2 < MK - 1) ? __expf(row[i0 + 2]) : 0.f;
    float e3 = (i0 + 3 < MK - 1) ? __expf(row[i0 + 3]) : 0.f;
    float p0 = e0, p1 = p0 + e1, p2 = p1 + e2, p3 = p2 + e3;
    float incl = p3;
#pragma unroll
    for (int off = 1; off < 64; off <<= 1) {
      float u = __shfl_up(incl, off, 64);
      if (lane >= off) incl += u;
    }
    float yv = y0[t];
    float base = yv + (incl - p3);
    if (lane == 0) syy[wid][0] = yv;
    if (i0 + 0 < MK - 1) syy[wid][1+i0+0] = base + p0;
    if (i0 + 1 < MK - 1) syy[wid][1+i0+1] = base + p1;
    if (i0 + 2 < MK - 1) syy[wid][1+i0+2] = base + p2;
    if (i0 + 3 < MK - 1) syy[wid][1+i0+3] = base + p3;
  }
  {
    const float* ld = logderiv + t * MK;
#pragma unroll
    for (int rep = 0; rep < 4; ++rep) {
      int m = lane + rep * 64;
      if (m < MK) sdel[wid][m] = __expf(ld[m]);
    }
  }
  __syncthreads();

#pragma unroll
  for (int rep = 0; rep < 4; ++rep) {
    int kk = lane + rep * 64;
    if (kk < MK - 1) {
      float xK = sxx[wid][kk], dx = sxx[wid][kk+1] - xK;
      float yK = syy[wid][kk], dy = syy[wid][kk+1] - yK;
      float rdx = 1.0f / dx;
      float s_ = dy * rdx;
      float dK = sdel[wid][kk], dK1 = sdel[wid][kk+1];
      ydk8[(t * (MK-1) + kk) * 2 + 0] = make_float4(xK, rdx, yK, dy);
      ydk8[(t * (MK-1) + kk) * 2 + 1] = make_float4(s_, dK, dK1, dK + dK1 - 2.f * s_);
    }
  }
  float xx0v = sxx[wid][0], xxMv = sxx[wid][MK-1];
  if (lane == 0) {
    float scale = (float)GB / (xxMv - xx0v);
    edge[t*2+0] = make_float4(xx0v, syy[wid][0],    sdel[wid][0],    scale);
    edge[t*2+1] = make_float4(xxMv, syy[wid][MK-1], sdel[wid][MK-1], 0.f);
  }
  float bw = (xxMv - xx0v) * (1.f / (float)GB);
#pragma unroll
  for (int i = 0; i < 4; ++i) {
    int g = lane * 4 + i;
    float L = xx0v + (float)g * bw;
    int p = 0;
#pragma unroll
    for (int st = 128; st >= 1; st >>= 1) {
      int cand = p + st;
      if (cand < MK && sxx[wid][cand] < L) p = cand;
    }
    gridb[t * GB + g] = (unsigned char)(p > MK-2 ? MK-2 : p);
  }
}

// ---------------------------------------------------------------------------
// Kernel G: transpose  data[n][dim] -> Xg[k][d][n]. Block = (row rr, 32 samp).
// float4 on both global sides; LDS pad 97 keeps conflicts <=2-way.
// ---------------------------------------------------------------------------
template<int CH>
__global__ __launch_bounds__(256) void gather_kernel(const float* __restrict__ data,
                                                     float* __restrict__ Xg,
                                                     int chunk_base) {
  const int tid = threadIdx.x;
  const int rr = blockIdx.x & 31, tile = blockIdx.x >> 5;
  const int q = (rr + 30) & 31;           // (rr-2) mod 32
  const int nh = q >> 2, kh = q & 3;
  const int n0 = tile * 32;
  __shared__ float sd[32][97];
#pragma unroll
  for (int it = 0; it < 3; ++it) {
    int i = tid + it * 256;               // 768 = 32 samples * 24 float4
    int s = i / 24, f4 = i % 24;
    float4 v = *(const float4*)(data + (size_t)(chunk_base + n0 + s) * NDIM + rr * 96 + f4 * 4);
    sd[s][f4*4+0] = v.x; sd[s][f4*4+1] = v.y; sd[s][f4*4+2] = v.z; sd[s][f4*4+3] = v.w;
  }
  __syncthreads();
#pragma unroll
  for (int it = 0; it < 3; ++it) {
    int o = tid + it * 256;               // 768 = 96 dims * 8 sample-quads
    int s4 = o & 7, p = o >> 3;
    int nw = p / 12, dd = p % 12;
    int c = 12 * nw + 6 + dd; c -= (c >= 96) ? 96 : 0;
    int k = nh * 8 + nw, d = kh * 12 + dd;
    float4 v = make_float4(sd[4*s4+0][c], sd[4*s4+1][c], sd[4*s4+2][c], sd[4*s4+3][c]);
    *(float4*)(Xg + ((size_t)(k * NS + d)) * CH + n0 + 4 * s4) = v;
  }
}

// ---------------------------------------------------------------------------
// Kernel C: per-patch core. Block = (patch k, 256 samples); LDS = xx + edge
// only (40 KB -> 4 blocks/CU). Bucket byte from global (L1); parallel refine;
// 32-B precomputed knot record. In-place Xg -> R.
// ---------------------------------------------------------------------------
template<int CH>
__global__ __launch_bounds__(256, 4) void core_kernel(
    float* __restrict__ Xg, const float* __restrict__ Qws,
    const float* __restrict__ xxg, const unsigned char* __restrict__ gridb,
    const float4* __restrict__ edge, const float4* __restrict__ ydk8,
    float* __restrict__ partial, int chunk_base) {
  const int tid = threadIdx.x;
  const int k = blockIdx.x & 63, tile = blockIdx.x >> 6;
  const int nl = tile * 256 + tid;
  __shared__ float sxx[NS * MK];
  __shared__ float4 sedge[NS * 2];
  for (int i = tid; i < NS * MK; i += 256) sxx[i] = xxg[k * NS * MK + i];
  if (tid < NS * 2) sedge[tid] = edge[k * NS * 2 + tid];
  __syncthreads();

  float* Xp = Xg + (size_t)k * NS * CH + nl;
  const float* Qk = Qws + k * NS * NS;
  const unsigned char* gk = gridb + (size_t)k * NS * GB;
  const float4* yk = ydk8 + (size_t)k * NS * (MK - 1) * 2;

  // --- phase A: d0 = x . Q ---
  float acc[NS];
#pragma unroll
  for (int j = 0; j < NS; ++j) acc[j] = 0.f;
#pragma unroll 4
  for (int d = 0; d < NS; ++d) {
    float xd = Xp[(size_t)d * CH];
    const float* qrow = Qk + d * NS;
#pragma unroll
    for (int j = 0; j < NS; ++j) acc[j] = fmaf(xd, qrow[j], acc[j]);
  }
  // --- phase B: spline, e = y - d0 ---
  float logsum = 0.f;
#pragma unroll 4
  for (int j = 0; j < NS; ++j) {
    float v = acc[j];
    float4 e0 = sedge[2*j], e1 = sedge[2*j+1];
    const float* xr = sxx + j * MK;
    int g = (int)((v - e0.x) * e0.w);
    g = g < 0 ? 0 : (g > GB-1 ? GB-1 : g);
    int kk = gk[j * GB + g];
    // parallel refine: monotone xx => independent compares sum correctly
    float xA = xr[imin(kk + 1, MK - 1)];
    float xB = xr[imin(kk + 2, MK - 1)];
    float xC = xr[imin(kk + 3, MK - 1)];
    kk += (int)(kk + 1 <= MK-2 && xA < v) + (int)(kk + 2 <= MK-2 && xB < v)
        + (int)(kk + 3 <= MK-2 && xC < v);
    float4 r0 = yk[(j * (MK-1) + kk) * 2 + 0];    // (xK, rdx, yK, dy)
    float4 r1 = yk[(j * (MK-1) + kk) * 2 + 1];    // (s, dK, dK1, d2s)
    float xi = (v - r0.x) * r0.y;
    xi = fminf(fmaxf(xi, 0.f), 1.f);
    float omxi = 1.f - xi, xi1 = xi * omxi, xi2 = xi * xi;
    float denom = fmaf(r1.w, xi1, r1.x);
    float rden = rcp_fast(denom);
    float y_in = fmaf(r0.w * fmaf(r1.x, xi2, r1.y * xi1), rden, r0.z);
    float d_in = r1.x * r1.x * (r1.z * xi2 + 2.f * r1.x * xi1 + r1.y * omxi * omxi) * (rden * rden);
    bool below = v <= e0.x, above = v > e1.x;
    float yv = below ? fmaf(e0.z, v - e0.x, e0.y)
             : (above ? fmaf(e1.z, v - e1.x, e1.y) : y_in);
    float dd = below ? e0.z : (above ? e1.z : d_in);
    logsum += __logf(dd);
    acc[j] = yv - v;
  }
  partial[k * NSMP + chunk_base + nl] = logsum;
  // --- phase C: R[d] = e . Q[d][:] ---
#pragma unroll 2
  for (int d = 0; d < NS; ++d) {
    const float* qrow = Qk + d * NS;
    float r0 = 0.f, r1 = 0.f, r2 = 0.f, r3 = 0.f;
#pragma unroll
    for (int j = 0; j < NS; j += 4) {
      r0 = fmaf(acc[j+0], qrow[j+0], r0);
      r1 = fmaf(acc[j+1], qrow[j+1], r1);
      r2 = fmaf(acc[j+2], qrow[j+2], r2);
      r3 = fmaf(acc[j+3], qrow[j+3], r3);
    }
    Xp[(size_t)d * CH] = (r0 + r1) + (r2 + r3);
  }
}

// ---------------------------------------------------------------------------
// Kernel S: out[n][dim] = data[n][dim] + untranspose(R).
// ---------------------------------------------------------------------------
template<int CH>
__global__ __launch_bounds__(256) void scatter_kernel(const float* __restrict__ data,
                                                      const float* __restrict__ R,
                                                      float* __restrict__ out,
                                                      int chunk_base) {
  const int tid = threadIdx.x;
  const int rr = blockIdx.x & 31, tile = blockIdx.x >> 5;
  const int q = (rr + 30) & 31;
  const int nh = q >> 2, kh = q & 3;
  const int n0 = tile * 32;
  __shared__ float sd[32][97];
#pragma unroll
  for (int it = 0; it < 3; ++it) {
    int o = tid + it * 256;
    int s4 = o & 7, p = o >> 3;
    int nw = p / 12, dd = p % 12;
    int c = 12 * nw + 6 + dd; c -= (c >= 96) ? 96 : 0;
    int k = nh * 8 + nw, d = kh * 12 + dd;
    float4 v = *(const float4*)(R + ((size_t)(k * NS + d)) * CH + n0 + 4 * s4);
    sd[4*s4+0][c] = v.x; sd[4*s4+1][c] = v.y; sd[4*s4+2][c] = v.z; sd[4*s4+3][c] = v.w;
  }
  __syncthreads();
#pragma unroll
  for (int it = 0; it < 3; ++it) {
    int i = tid + it * 256;
    int s = i / 24, f4 = i % 24;
    size_t off = (size_t)(chunk_base + n0 + s) * NDIM + rr * 96 + f4 * 4;
    float4 v = *(const float4*)(data + off);
    v.x += sd[s][f4*4+0]; v.y += sd[s][f4*4+1];
    v.z += sd[s][f4*4+2]; v.w += sd[s][f4*4+3];
    *(float4*)(out + off) = v;
  }
}

__global__ __launch_bounds__(256) void reduce_kernel(const float* __restrict__ partial,
                                                     float* __restrict__ logj) {
  int n = blockIdx.x * 256 + threadIdx.x;
  float s = 0.f;
#pragma unroll
  for (int k = 0; k < NK; ++k) s += partial[k * NSMP + n];
  logj[n] = s;
}

template<int CH>
static void run_pipeline(const float* data, const float* Araw, const float* x0,
                         const float* logdx, const float* y0, const float* logdy,
                         const float* logderiv, float* out, float* ws,
                         hipStream_t stream) {
  float*         Qws   = ws;                                 // 589,824 B
  float*         xxg   = Qws  + 64 * NS * NS;                // 2,457,600 B
  float4*        ydk8  = (float4*)(xxg + 3072 * MK);         // 19,562,496 B
  float4*        edge  = ydk8 + 3072 * (MK - 1) * 2;         // 98,304 B
  unsigned char* gridb = (unsigned char*)(edge + 3072 * 2);  // 786,432 B
  float*         Xg    = (float*)(gridb + 3072 * GB);        // 12288*CH B
  float*         partial = Xg + (size_t)NK * NS * CH;        // 2,097,152 B

  qr_kernel<<<64, 64, 0, stream>>>(Araw, Qws);
  knots_kernel<<<768, 256, 0, stream>>>(x0, logdx, y0, logdy, logderiv,
                                        xxg, ydk8, edge, gridb);
  for (int c = 0; c < NSMP / CH; ++c) {
    const int base = c * CH;
    gather_kernel<CH> <<<CH,     256, 0, stream>>>(data, Xg, base);
    core_kernel<CH>   <<<CH / 4, 256, 0, stream>>>(Xg, Qws, xxg, gridb, edge, ydk8,
                                                   partial, base);
    scatter_kernel<CH><<<CH,     256, 0, stream>>>(data, Xg, out, base);
  }
  reduce_kernel<<<32, 256, 0, stream>>>(partial, out + (size_t)NSMP * NDIM);
}

extern "C" void kernel_launch(void* const* d_in, const int* in_sizes, int n_in,
                              void* d_out, int out_size, void* d_ws, size_t ws_size,
                              hipStream_t stream) {
  const float* data     = (const float*)d_in[0];
  const float* Araw     = (const float*)d_in[1];
  const float* x0       = (const float*)d_in[2];
  const float* logdx    = (const float*)d_in[3];
  const float* y0       = (const float*)d_in[4];
  const float* logdy    = (const float*)d_in[5];
  const float* logderiv = (const float*)d_in[6];
  float* out = (float*)d_out;
  float* ws  = (float*)d_ws;

  const size_t fixed = 589824 + 2457600 + 19562496 + 98304 + 786432 + 2097152;
  if (ws_size >= fixed + (size_t)12288 * 8192)
    run_pipeline<8192>(data, Araw, x0, logdx, y0, logdy, logderiv, out, ws, stream);
  else if (ws_size >= fixed + (size_t)12288 * 4096)
    run_pipeline<4096>(data, Araw, x0, logdx, y0, logdy, logderiv, out, ws, stream);
  else
    run_pipeline<2048>(data, Araw, x0, logdx, y0, logdy, logderiv, out, ws, stream);
}